// Round 4
// baseline (512.333 us; speedup 1.0000x reference)
//
#include <hip/hip_runtime.h>
#include <hip/hip_bf16.h>

#define NN 50000
#define CC 64
#define GG 3
#define EE 1200000
#define LL 2
#define DD 256
#define HH 256
#define NB 196              // dst buckets of 256 nodes
#define NBLK 293            // ceil(EE/4096) edge chunks per graph (bhist)
#define NBK (GG * NB)       // 588 (g,bucket) pairs
#define BKCAP 8192          // per-(g,bucket) LDS staging cap (mean 6122, sigma 78)
#define CH 16384            // binA chunk (edges) - LDS-sorted then flushed
#define CBLK 74             // ceil(EE/CH) chunks per graph

// Staged edge record (8B): x = bf16(e0)<<16 | bf16(e1); y = src<<16 | dst_local.
// Final per-layer packed word (4B): bf16(a)<<16 | src  (src < 2^16).
// Gather tables (lab_bf, h_buf) are stored as TWO CLASS-PLANES [NN][32]
// (3.2MB each -> fits 4MB per-XCD L2; rows 64B). Waves keep the packed tile
// in registers and run it once per plane -> no extra packed reads.
// labels_oh * train_mask is one-hot-or-zero -> precomputed mid[v] (class or -1).
// Softmax: e = 0.1*N(0,1) -> exp() needs no max-subtraction.

__device__ __forceinline__ ushort f2bf(float f) {
    unsigned b = __float_as_uint(f);
    return (ushort)((b + 0x7fffu + ((b >> 16) & 1u)) >> 16);
}
__device__ __forceinline__ float bf2f(unsigned u) {
    return __uint_as_float(u << 16);
}

// ---------------------------------------------------------------------------
// MFMA bf16 GEMM (unchanged from round 2)
// ---------------------------------------------------------------------------
typedef __attribute__((ext_vector_type(8))) short s8v;
typedef __attribute__((ext_vector_type(4))) float f4v;

template<int NWM, int NWN, bool A_FP32, bool OUT_RELU_BF16>
__global__ __launch_bounds__(256) void mfma_gemm_kernel(
    const void* __restrict__ Av, const ushort* __restrict__ Bt,
    const float* __restrict__ bias, void* __restrict__ Cv, int M, int Nc)
{
    static_assert(NWM * NWN == 4, "4 waves per block");
    const int tid = threadIdx.x;
    const int w = tid >> 6;
    const int l = tid & 63;
    const int wm = w / NWN;
    const int wn = w % NWN;
    const int r0 = blockIdx.x * (NWM * 64) + wm * 64;
    const int c0 = blockIdx.y * (NWN * 64) + wn * 64;
    const int lrow = l & 15;
    const int lk = (l >> 4) << 3;

    f4v acc[4][4] = {};

    for (int k0 = 0; k0 < 256; k0 += 32) {
        s8v a[4], b[4];
        #pragma unroll
        for (int i = 0; i < 4; i++) {
            int row = r0 + lrow + 16 * i;
            row = (row < M) ? row : (M - 1);
            if constexpr (A_FP32) {
                const float* Af = (const float*)Av;
                const float4* p = (const float4*)(Af + (size_t)row * 256 + k0 + lk);
                float4 f0 = p[0], f1 = p[1];
                union { ushort u[8]; s8v v; } t;
                t.u[0] = f2bf(f0.x); t.u[1] = f2bf(f0.y);
                t.u[2] = f2bf(f0.z); t.u[3] = f2bf(f0.w);
                t.u[4] = f2bf(f1.x); t.u[5] = f2bf(f1.y);
                t.u[6] = f2bf(f1.z); t.u[7] = f2bf(f1.w);
                a[i] = t.v;
            } else {
                const ushort* Ab = (const ushort*)Av;
                a[i] = *(const s8v*)(Ab + (size_t)row * 256 + k0 + lk);
            }
        }
        #pragma unroll
        for (int j = 0; j < 4; j++) {
            int col = c0 + lrow + 16 * j;
            b[j] = *(const s8v*)(Bt + (size_t)col * 256 + k0 + lk);
        }
        #pragma unroll
        for (int i = 0; i < 4; i++)
            #pragma unroll
            for (int j = 0; j < 4; j++)
                acc[i][j] = __builtin_amdgcn_mfma_f32_16x16x32_bf16(
                    a[i], b[j], acc[i][j], 0, 0, 0);
    }

    #pragma unroll
    for (int i = 0; i < 4; i++) {
        #pragma unroll
        for (int r = 0; r < 4; r++) {
            int row = r0 + 16 * i + (l >> 4) * 4 + r;
            if (row >= M) continue;
            #pragma unroll
            for (int j = 0; j < 4; j++) {
                int col = c0 + 16 * j + lrow;
                float v = acc[i][j][r] + bias[col];
                if constexpr (OUT_RELU_BF16) {
                    v = fmaxf(v, 0.f);
                    ((ushort*)Cv)[(size_t)row * Nc + col] = f2bf(v);
                } else {
                    ((float*)Cv)[(size_t)row * Nc + col] = v;
                }
            }
        }
    }
}

// ---------------------------------------------------------------------------
// Weight transpose + bf16 convert (unchanged)
// ---------------------------------------------------------------------------
__global__ void wcvt_kernel(const float* __restrict__ W1,
                            const float* __restrict__ W2,
                            ushort* __restrict__ Wt1, ushort* __restrict__ Wt2)
{
    int idx = blockIdx.x * 256 + threadIdx.x;
    if (idx < 256 * 256) {
        int n = idx >> 8, k = idx & 255;
        Wt1[idx] = f2bf(W1[k * 256 + n]);
    } else {
        int i = idx - 256 * 256;
        if (i < 64 * 256) {
            int n = i >> 8, k = i & 255;
            Wt2[i] = f2bf(W2[k * 64 + n]);
        }
    }
}

// ---------------------------------------------------------------------------
// Prep: (a) label_init -> bf16 two-plane table; (b) mid[v] = train ? cls : -1
// Blocks [0,3125): cvt (800000 ushort4 groups). Blocks [3125,6250): mid,
// 16 nodes/block, 16 lanes/node (one-hot dot-product index extraction).
// ---------------------------------------------------------------------------
__global__ __launch_bounds__(256) void prep_kernel(
    const float* __restrict__ label_init, const float* __restrict__ labels_oh,
    const float* __restrict__ train_mask, ushort* __restrict__ lab_bf,
    short* __restrict__ mid)
{
    int b = blockIdx.x;
    if (b < 3125) {
        int i = b * 256 + threadIdx.x;          // [0, 800000)
        int v = i >> 4;
        int c4 = (i & 15) * 4;
        float4 f = ((const float4*)label_init)[i];
        ushort4 u;
        u.x = f2bf(f.x); u.y = f2bf(f.y); u.z = f2bf(f.z); u.w = f2bf(f.w);
        int pl = c4 >> 5;
        *(ushort4*)(lab_bf + (size_t)pl * NN * 32 + (size_t)v * 32 + (c4 & 31)) = u;
    } else {
        int t = threadIdx.x;
        int v = (b - 3125) * 16 + (t >> 4);
        int sl = t & 15;
        if (v < NN) {
            float4 f = ((const float4*)(labels_oh + (size_t)v * 64))[sl];
            float p = (float)(sl * 4);
            float s = f.x * p + f.y * (p + 1.f) + f.z * (p + 2.f) + f.w * (p + 3.f);
            s += __shfl_xor(s, 1); s += __shfl_xor(s, 2);
            s += __shfl_xor(s, 4); s += __shfl_xor(s, 8);
            if (sl == 0) {
                float tm = train_mask[v];
                mid[v] = (tm > 0.5f) ? (short)(s + 0.5f) : (short)-1;
            }
        }
    }
}

// ---------------------------------------------------------------------------
// Bucket-level histogram (unchanged)
// ---------------------------------------------------------------------------
__global__ __launch_bounds__(256) void bhist_kernel(
    const int* __restrict__ dst, int* __restrict__ bcnt)
{
    int blk = blockIdx.x;
    int g = blk / NBLK;
    int bi = blk - g * NBLK;
    int base = bi * 4096;
    __shared__ int cnt[NB];
    int t = threadIdx.x;
    if (t < NB) cnt[t] = 0;
    __syncthreads();
    #pragma unroll
    for (int k = 0; k < 16; k++) {
        int e = base + k * 256 + t;
        if (e < EE) atomicAdd(&cnt[dst[g * EE + e] >> 8], 1);
    }
    __syncthreads();
    if (t < NB && cnt[t] > 0) atomicAdd(&bcnt[g * NB + t], cnt[t]);
}

// ---------------------------------------------------------------------------
// Scan 588 bucket counts (unchanged)
// ---------------------------------------------------------------------------
__global__ void scan_bucket(const int* __restrict__ bcnt, int* __restrict__ bs)
{
    __shared__ int sd[256];
    __shared__ int s_run;
    int t = threadIdx.x;
    if (t == 0) s_run = 0;
    __syncthreads();
    for (int base = 0; base < NBK; base += 256) {
        int i = base + t;
        int v = (i < NBK) ? bcnt[i] : 0;
        sd[t] = v;
        __syncthreads();
        for (int o = 1; o < 256; o <<= 1) {
            int x = (t >= o) ? sd[t - o] : 0;
            __syncthreads();
            sd[t] += x;
            __syncthreads();
        }
        int run = s_run;
        __syncthreads();
        if (i < NBK) bs[i] = run + sd[t] - v;
        if (t == 255) s_run = run + sd[255];
        __syncthreads();
    }
    if (t == 0) bs[NBK] = GG * EE;
}

// ---------------------------------------------------------------------------
// Phase A: LDS-sorted chunk binning (unchanged from round 3)
// ---------------------------------------------------------------------------
__global__ __launch_bounds__(1024) void binA_kernel(
    const int* __restrict__ dst, const int* __restrict__ src,
    const float* __restrict__ e_edges, const int* __restrict__ bucket_start,
    int* __restrict__ fill, uint2* __restrict__ staging)
{
    int blk = blockIdx.x;
    int g = blk / CBLK;
    int bi = blk - g * CBLK;
    int base = bi * CH;
    __shared__ uint2 rec[CH];
    __shared__ int cnt[NB];
    __shared__ int lstart[NB];
    __shared__ int cur[NB];
    __shared__ int gbase[NB];
    __shared__ int sd[256];
    int t = threadIdx.x;
    if (t < NB) cnt[t] = 0;
    __syncthreads();

    int myd[16];
    #pragma unroll
    for (int k = 0; k < 16; k++) {
        int e = base + k * 1024 + t;
        int d = (e < EE) ? dst[g * EE + e] : -1;
        myd[k] = d;
        if (d >= 0) atomicAdd(&cnt[d >> 8], 1);
    }
    __syncthreads();

    if (t < 256) sd[t] = (t < NB) ? cnt[t] : 0;
    __syncthreads();
    for (int o = 1; o < 256; o <<= 1) {
        int x = (t < 256 && t >= o) ? sd[t - o] : 0;
        __syncthreads();
        if (t < 256) sd[t] += x;
        __syncthreads();
    }
    if (t < NB) {
        int c = cnt[t];
        int ls = sd[t] - c;
        lstart[t] = ls;
        cur[t] = ls;
        int fo = (c > 0) ? atomicAdd(&fill[g * NB + t], c) : 0;
        gbase[t] = bucket_start[g * NB + t] + fo;
    }
    __syncthreads();

    #pragma unroll
    for (int k = 0; k < 16; k++) {
        int d = myd[k];
        if (d >= 0) {
            int e = base + k * 1024 + t;
            int pos = atomicAdd(&cur[d >> 8], 1);
            int idxg = g * EE + e;
            uint2 r;
            r.x = ((unsigned)f2bf(e_edges[idxg]) << 16) |
                  (unsigned)f2bf(e_edges[(size_t)(GG + g) * EE + e]);
            r.y = ((unsigned)src[idxg] << 16) | (unsigned)(d & 255);
            rec[pos] = r;
        }
    }
    __syncthreads();

    int w = t >> 6, lane = t & 63;
    for (int b = w; b < NB; b += 16) {
        int c = cnt[b];
        int ls = lstart[b];
        uint2* dp = staging + gbase[b];
        for (int i = lane; i < c; i += 64) dp[i] = rec[ls + i];
    }
}

// ---------------------------------------------------------------------------
// Phase B: per-bucket order + softmax (unchanged from round 3)
// ---------------------------------------------------------------------------
__global__ __launch_bounds__(1024) void bucket_kernel(
    const uint2* __restrict__ staging, const int* __restrict__ bucket_start,
    int* __restrict__ row_start, unsigned* __restrict__ packed0,
    unsigned* __restrict__ packed1)
{
    int blk = blockIdx.x;
    int g = blk / NB;
    int bucket = blk - g * NB;
    int bn = bucket << 8;
    int bnodes = min(256, NN - bn);
    int sbase = bucket_start[blk];
    int n = bucket_start[blk + 1] - sbase;
    int segStart = sbase - g * EE;
    const uint2* st = staging + sbase;

    __shared__ int hist[256];
    __shared__ int sd[256];
    __shared__ int cur[256];
    __shared__ float sm[512];
    __shared__ ushort ab0[BKCAP];
    __shared__ ushort ab1[BKCAP];
    __shared__ ushort sb[BKCAP];
    int t = threadIdx.x;
    if (t < 256) hist[t] = 0;
    if (t < 512) sm[t] = 0.f;
    __syncthreads();

    for (int i = t; i < n; i += 1024) {
        uint2 r = st[i];
        int dl = r.y & 0xff;
        atomicAdd(&hist[dl], 1);
        atomicAdd(&sm[dl], __expf(bf2f(r.x >> 16)));
        atomicAdd(&sm[256 + dl], __expf(bf2f(r.x & 0xffffu)));
    }
    __syncthreads();

    if (t < 256) sd[t] = hist[t];
    __syncthreads();
    for (int o = 1; o < 256; o <<= 1) {
        int x = (t < 256 && t >= o) ? sd[t - o] : 0;
        __syncthreads();
        if (t < 256) sd[t] += x;
        __syncthreads();
    }
    if (t < 256) {
        cur[t] = sd[t] - hist[t];
        if (t < bnodes)
            row_start[(size_t)g * (NN + 1) + bn + t] = segStart + sd[t] - hist[t];
        if (hist[t] > 0) {
            sm[t] = 1.f / sm[t];
            sm[256 + t] = 1.f / sm[256 + t];
        }
    }
    if (bucket == NB - 1 && t == 0) row_start[(size_t)g * (NN + 1) + NN] = EE;
    __syncthreads();

    for (int i = t; i < n; i += 1024) {
        uint2 r = st[i];
        int dl = r.y & 0xff;
        int pos = atomicAdd(&cur[dl], 1);
        ab0[pos] = f2bf(__expf(bf2f(r.x >> 16)) * sm[dl]);
        ab1[pos] = f2bf(__expf(bf2f(r.x & 0xffffu)) * sm[256 + dl]);
        sb[pos] = (ushort)(r.y >> 16);
    }
    __syncthreads();

    for (int i = t; i < n; i += 1024) {
        unsigned s = sb[i];
        packed0[(size_t)sbase + i] = ((unsigned)ab0[i] << 16) | s;
        packed1[(size_t)sbase + i] = ((unsigned)ab1[i] << 16) | s;
    }
}

// ---------------------------------------------------------------------------
// Plane gather: one 64B row per 8 lanes (dwordx2 = 4 classes/lane), 8 edges
// per load instruction, 4 loads in flight. packed tile lives in registers;
// lanes past tE carry packed=0 (weight +0, row 0) -> self-masking.
// ---------------------------------------------------------------------------
__device__ __forceinline__ void tile_pass(unsigned packed, int cnt,
        const ushort* __restrict__ plane, unsigned loff, int sub, float acc[4])
{
    for (int q0 = 0; q0 < cnt; q0 += 32) {
        uint2 gv[4]; float w[4];
        #pragma unroll
        for (int u = 0; u < 4; u++) {
            unsigned pkq = __shfl(packed, q0 + 8 * u + sub);
            w[u] = __uint_as_float(pkq & 0xffff0000u);
            gv[u] = *(const uint2*)((const char*)plane +
                                    (((pkq & 0xffffu) << 6) | loff));
        }
        #pragma unroll
        for (int u = 0; u < 4; u++) {
            acc[0] = fmaf(__uint_as_float(gv[u].x << 16),          w[u], acc[0]);
            acc[1] = fmaf(__uint_as_float(gv[u].x & 0xffff0000u),  w[u], acc[1]);
            acc[2] = fmaf(__uint_as_float(gv[u].y << 16),          w[u], acc[2]);
            acc[3] = fmaf(__uint_as_float(gv[u].y & 0xffff0000u),  w[u], acc[3]);
        }
    }
}

// ---------------------------------------------------------------------------
// Layer 0 propagation: wave per (g,node); two-plane gather; mid[] blend.
// ---------------------------------------------------------------------------
__global__ __launch_bounds__(256) void prop0_kernel(
    const ushort* __restrict__ lab_bf, const short* __restrict__ mid,
    const int* __restrict__ row_start, const unsigned* __restrict__ packed0,
    ushort* __restrict__ h_buf)
{
    int wid = (blockIdx.x * blockDim.x + threadIdx.x) >> 6;
    int lane = threadIdx.x & 63;
    if (wid >= GG * NN) return;
    int g = wid / NN;
    int v = wid - g * NN;
    const int* rs = row_start + (size_t)g * (NN + 1);
    int s = rs[v], tE = rs[v + 1];
    const unsigned* pk = packed0 + (size_t)g * EE;
    const ushort* pl0 = lab_bf;
    const ushort* pl1 = lab_bf + (size_t)NN * 32;

    unsigned loff = (lane & 7) << 3;
    int sub = lane >> 3;
    float a0[4] = {}, a1[4] = {};
    for (int base = s; base < tE; base += 64) {
        int j = base + lane;
        unsigned packed = (j < tE) ? pk[j] : 0u;
        int cnt = min(64, tE - base);
        tile_pass(packed, cnt, pl0, loff, sub, a0);
        tile_pass(packed, cnt, pl1, loff, sub, a1);
    }
    #pragma unroll
    for (int c = 0; c < 4; c++) {
        a0[c] += __shfl_xor(a0[c], 8);
        a0[c] += __shfl_xor(a0[c], 16);
        a0[c] += __shfl_xor(a0[c], 32);
        a1[c] += __shfl_xor(a1[c], 8);
        a1[c] += __shfl_xor(a1[c], 16);
        a1[c] += __shfl_xor(a1[c], 32);
    }
    int m = mid[v];
    float ml = (m < 0) ? 1.f : 0.f;
    ushort* hg = h_buf + (size_t)g * NN * 64;
    int cb = (lane & 7) * 4;
    if (lane < 8) {
        ushort4 o;
        o.x = f2bf(a0[0] * ml + ((cb + 0 == m) ? 1.f : 0.f));
        o.y = f2bf(a0[1] * ml + ((cb + 1 == m) ? 1.f : 0.f));
        o.z = f2bf(a0[2] * ml + ((cb + 2 == m) ? 1.f : 0.f));
        o.w = f2bf(a0[3] * ml + ((cb + 3 == m) ? 1.f : 0.f));
        *(ushort4*)(hg + (size_t)v * 32 + cb) = o;
    } else if (lane < 16) {
        int cc = cb + 32;
        ushort4 o;
        o.x = f2bf(a1[0] * ml + ((cc + 0 == m) ? 1.f : 0.f));
        o.y = f2bf(a1[1] * ml + ((cc + 1 == m) ? 1.f : 0.f));
        o.z = f2bf(a1[2] * ml + ((cc + 2 == m) ? 1.f : 0.f));
        o.w = f2bf(a1[3] * ml + ((cc + 3 == m) ? 1.f : 0.f));
        *(ushort4*)(hg + (size_t)NN * 32 + (size_t)v * 32 + cb) = o;
    }
}

// ---------------------------------------------------------------------------
// Layer 1 + attention combine + alpha mix: wave per node, two-plane gather.
// moh folds out of the g-sum (sum attw = 1): lp = wacc*ml + moh.
// ---------------------------------------------------------------------------
__global__ __launch_bounds__(256) void final_kernel(
    const ushort* __restrict__ h_buf, const short* __restrict__ mid,
    const float* __restrict__ attention, const float* __restrict__ alpha,
    const int* __restrict__ row_start, const unsigned* __restrict__ packed1,
    const float* __restrict__ out_ns, float* __restrict__ out_logits,
    float* __restrict__ out_lp)
{
    int wid = (blockIdx.x * blockDim.x + threadIdx.x) >> 6;
    int lane = threadIdx.x & 63;
    if (wid >= NN) return;
    int v = wid;
    float t0 = attention[v * 3], t1 = attention[v * 3 + 1], t2 = attention[v * 3 + 2];
    float mxa = fmaxf(t0, fmaxf(t1, t2));
    float e0 = __expf(t0 - mxa), e1 = __expf(t1 - mxa), e2 = __expf(t2 - mxa);
    float ainv = 1.f / (e0 + e1 + e2);
    float attw[3] = {e0 * ainv, e1 * ainv, e2 * ainv};

    unsigned loff = (lane & 7) << 3;
    int sub = lane >> 3;
    float w0[4] = {}, w1[4] = {};
    #pragma unroll
    for (int g = 0; g < GG; g++) {
        const int* rs = row_start + (size_t)g * (NN + 1);
        int s = rs[v], tE = rs[v + 1];
        const unsigned* pk = packed1 + (size_t)g * EE;
        const ushort* hp0 = h_buf + (size_t)g * NN * 64;
        const ushort* hp1 = hp0 + (size_t)NN * 32;
        float b0[4] = {}, b1[4] = {};
        for (int base = s; base < tE; base += 64) {
            int j = base + lane;
            unsigned packed = (j < tE) ? pk[j] : 0u;
            int cnt = min(64, tE - base);
            tile_pass(packed, cnt, hp0, loff, sub, b0);
            tile_pass(packed, cnt, hp1, loff, sub, b1);
        }
        float aw = attw[g];
        #pragma unroll
        for (int c = 0; c < 4; c++) {
            w0[c] = fmaf(aw, b0[c], w0[c]);
            w1[c] = fmaf(aw, b1[c], w1[c]);
        }
    }
    #pragma unroll
    for (int c = 0; c < 4; c++) {
        w0[c] += __shfl_xor(w0[c], 8);
        w0[c] += __shfl_xor(w0[c], 16);
        w0[c] += __shfl_xor(w0[c], 32);
        w1[c] += __shfl_xor(w1[c], 8);
        w1[c] += __shfl_xor(w1[c], 16);
        w1[c] += __shfl_xor(w1[c], 32);
    }
    int m = mid[v];
    float ml = (m < 0) ? 1.f : 0.f;
    if (lane < 16) {
        int pl = lane >> 3;
        int cb = (lane & 7) * 4 + pl * 32;
        float4 lpv;
        if (pl == 0) {
            lpv.x = w0[0] * ml + ((cb + 0 == m) ? 1.f : 0.f);
            lpv.y = w0[1] * ml + ((cb + 1 == m) ? 1.f : 0.f);
            lpv.z = w0[2] * ml + ((cb + 2 == m) ? 1.f : 0.f);
            lpv.w = w0[3] * ml + ((cb + 3 == m) ? 1.f : 0.f);
        } else {
            lpv.x = w1[0] * ml + ((cb + 0 == m) ? 1.f : 0.f);
            lpv.y = w1[1] * ml + ((cb + 1 == m) ? 1.f : 0.f);
            lpv.z = w1[2] * ml + ((cb + 2 == m) ? 1.f : 0.f);
            lpv.w = w1[3] * ml + ((cb + 3 == m) ? 1.f : 0.f);
        }
        size_t o = (size_t)v * 64 + cb;
        *(float4*)(out_lp + o) = lpv;
        float al = alpha[v];
        float sg = 1.f / (1.f + __expf(-al));
        float4 ns = *(const float4*)(out_ns + o);
        float4 lg;
        lg.x = sg * lpv.x + (1.f - sg) * ns.x;
        lg.y = sg * lpv.y + (1.f - sg) * ns.y;
        lg.z = sg * lpv.z + (1.f - sg) * ns.z;
        lg.w = sg * lpv.w + (1.f - sg) * ns.w;
        *(float4*)(out_logits + o) = lg;
    }
}

// ---------------------------------------------------------------------------
extern "C" void kernel_launch(void* const* d_in, const int* in_sizes, int n_in,
                              void* d_out, int out_size, void* d_ws, size_t ws_size,
                              hipStream_t stream)
{
    const float* features0  = (const float*)d_in[0];
    const float* label_init = (const float*)d_in[1];
    const float* labels_oh  = (const float*)d_in[2];
    const float* train_mask = (const float*)d_in[3];
    const int*   src        = (const int*)d_in[4];
    const int*   dst        = (const int*)d_in[5];
    const float* e_edges    = (const float*)d_in[6];
    const float* attention  = (const float*)d_in[7];
    const float* alpha      = (const float*)d_in[8];
    const float* W1         = (const float*)d_in[9];
    const float* b1         = (const float*)d_in[10];
    const float* W2         = (const float*)d_in[11];
    const float* b2         = (const float*)d_in[12];

    float* out        = (float*)d_out;
    float* out_logits = out;
    float* out_lp     = out + (size_t)NN * CC;
    float* out_ns     = out + 2 * (size_t)NN * CC;

    char* base = (char*)d_ws;
    size_t off = 0;
    auto alloc = [&](size_t bytes) -> void* {
        void* p = base + off;
        off = (off + bytes + 255) & ~(size_t)255;
        return p;
    };
    int*      bcnt         = (int*)alloc((size_t)NBK * sizeof(int));
    int*      fill         = (int*)alloc((size_t)NBK * sizeof(int));
    size_t    zero_bytes   = off;
    int*      bucket_start = (int*)alloc((size_t)(NBK + 1) * sizeof(int));
    int*      row_start    = (int*)alloc((size_t)GG * (NN + 1) * sizeof(int));
    uint2*    staging      = (uint2*)alloc((size_t)GG * EE * sizeof(uint2));
    unsigned* packed0      = (unsigned*)alloc((size_t)GG * EE * sizeof(unsigned));
    unsigned* packed1      = (unsigned*)alloc((size_t)GG * EE * sizeof(unsigned));
    ushort*   h_buf        = (ushort*)alloc((size_t)GG * NN * CC * sizeof(ushort));
    ushort*   lab_bf       = (ushort*)alloc((size_t)NN * CC * sizeof(ushort));
    short*    mid          = (short*)alloc((size_t)NN * sizeof(short));

    // Aliased MLP scratch (stream-ordered reuse):
    //  - Wt1/Wt2 in packed0's region (read by gemm2 before bucket writes it)
    //  - hm_bf in staging's region (read by gemm2 before binA writes it)
    ushort* Wt1   = (ushort*)packed0;
    ushort* Wt2   = Wt1 + 256 * 256;
    ushort* hm_bf = (ushort*)staging;

    // ---- MLP: logits_ns = relu(features0 @ W1 + b1) @ W2 + b2, bf16 MFMA ----
    wcvt_kernel<<<(256 * 256 + 64 * 256) / 256, 256, 0, stream>>>(W1, W2, Wt1, Wt2);
    mfma_gemm_kernel<2, 2, true, true><<<dim3((NN + 127) / 128, 2), 256, 0, stream>>>(
        features0, Wt1, b1, hm_bf, NN, HH);
    mfma_gemm_kernel<4, 1, false, false><<<dim3((NN + 255) / 256, 1), 256, 0, stream>>>(
        hm_bf, Wt2, b2, out_ns, NN, CC);

    // ---- prep: two-plane bf16 label table + mid[] ----
    prep_kernel<<<6250, 256, 0, stream>>>(label_init, labels_oh, train_mask,
                                          lab_bf, mid);

    // ---- CSR build ----
    hipMemsetAsync(bcnt, 0, zero_bytes, stream);
    bhist_kernel<<<GG * NBLK, 256, 0, stream>>>(dst, bcnt);
    scan_bucket<<<1, 256, 0, stream>>>(bcnt, bucket_start);
    binA_kernel<<<GG * CBLK, 1024, 0, stream>>>(
        dst, src, e_edges, bucket_start, fill, staging);
    bucket_kernel<<<GG * NB, 1024, 0, stream>>>(
        staging, bucket_start, row_start, packed0, packed1);

    // ---- Layer 0 propagation ----
    prop0_kernel<<<((size_t)GG * NN * 64 + 255) / 256, 256, 0, stream>>>(
        lab_bf, mid, row_start, packed0, h_buf);

    // ---- Layer 1 + attention combine + alpha mix ----
    final_kernel<<<((size_t)NN * 64 + 255) / 256, 256, 0, stream>>>(
        h_buf, mid, attention, alpha, row_start, packed1,
        out_ns, out_logits, out_lp);
}